// Round 10
// baseline (132.761 us; speedup 1.0000x reference)
//
#include <hip/hip_runtime.h>
#include <hip/hip_bf16.h>

#define SIZE 4096
#define BM 256
#define BK 64
#define NT (SIZE / BK)     // 64 K-tiles
#define NBG (SIZE / BM)    // 16x16 grid of 256^2 tiles

typedef __bf16 bf16x8 __attribute__((ext_vector_type(8)));
typedef __bf16 bf16x4 __attribute__((ext_vector_type(4)));
typedef float f32x4 __attribute__((ext_vector_type(4)));
typedef float f32x16 __attribute__((ext_vector_type(16)));

__device__ __forceinline__ void gload_lds16(const void* gsrc, void* ldst) {
  __builtin_amdgcn_global_load_lds(
      (const __attribute__((address_space(1))) unsigned int*)gsrc,
      (__attribute__((address_space(3))) unsigned int*)ldst, 16, 0, 0);
}

// ---------------------------------------------------------------------------
// Kernel 1: build L (bf16). One 256-thread block per row. 4 cols/thread.
// fp32 throughout (matches reference underflow).
// ---------------------------------------------------------------------------
__global__ __launch_bounds__(256) void build_L(const float* __restrict__ p,
                                               __bf16* __restrict__ Lb) {
  const int row = blockIdx.x;
  const int tid = threadIdx.x;
  const int lane = tid & 63;
  const int wid = tid >> 6;
  const long base = (long)row * (row - 1) / 2;

  __shared__ float wtot[4];
  float carry = 1.0f;

  for (int j0 = 0; j0 < SIZE; j0 += 1024) {
    const int jb = j0 + tid * 4;
    if (j0 > row) {
      bf16x4 z = {(__bf16)0.0f, (__bf16)0.0f, (__bf16)0.0f, (__bf16)0.0f};
      *(bf16x4*)&Lb[(size_t)row * SIZE + jb] = z;
      continue;
    }
    float t[4], v[4];
#pragma unroll
    for (int e = 0; e < 4; ++e) {
      const int j = jb + e;
      if (j < row) {
        const float th = tanhf(p[base + j]);
        t[e] = th;
        v[e] = 1.0f - th * th;
      } else {
        t[e] = (j == row) ? 1.0f : 0.0f;
        v[e] = 1.0f;
      }
    }
    const float vt = v[0] * v[1] * v[2] * v[3];
    float incl = vt;
#pragma unroll
    for (int off = 1; off < 64; off <<= 1) {
      float o = __shfl_up(incl, off, 64);
      if (lane >= off) incl *= o;
    }
    if (lane == 63) wtot[wid] = incl;
    __syncthreads();
    float pre = carry;
    for (int w = 0; w < wid; ++w) pre *= wtot[w];
    float excl = __shfl_up(incl, 1, 64);
    if (lane == 0) excl = 1.0f;
    float s = pre * excl;
    bf16x4 out;
#pragma unroll
    for (int e = 0; e < 4; ++e) {
      out[e] = (__bf16)(t[e] * sqrtf(s));
      s *= v[e];
    }
    *(bf16x4*)&Lb[(size_t)row * SIZE + jb] = out;
    const float tot = wtot[0] * wtot[1] * wtot[2] * wtot[3];
    __syncthreads();
    carry *= tot;
  }
}

// ---------------------------------------------------------------------------
// Kernel 2: C = L*L^T, 256x256 tile, *** 4 waves (2x2), 128x128 per wave ***
// Rationale: LDS read traffic/CU/tile = (WARPS_N*BM + WARPS_M*BN)*BK*2B:
// 8 waves (2x4) -> 192 KB; 4 waves (2x2) -> 128 KB. Per-CU LDS pipe was the
// measured pole (R5..R9 all ~4350 cyc/tile = 2066 MFMA + ~2300 LDS, no
// overlap). Now LDS ~1730 < MFMA 2066: MFMA becomes the pole.
// 32x32x16 MFMA, chunk-XOR swizzle (0 conflicts, R7-R9), R9's counted
// lgkm/vmcnt 4-phase skeleton re-derived for 4-load stages:
//   reads/phase: ph0:4(afB kh0mh1) ph1:12(afA kh1mh0+bfB kh1) ph2:4(afB
//   kh1mh1) ph3:12(next-tile afA+bfA kh0);  LGKM(4/12/4/12) = exact counts.
// Stage ledger (stg = 4 gloads; region last-readers confirmed before stg):
//   ph0 stg nbuf A-kh1: prev tile's kh1 reads confirmed by prev ph3 LGKM +
//       final barrier.
//   ph1 stg buf B-kh0 : bfA LDS-reads were prev ph3, confirmed ph0 LGKM(4)
//       + ph0 barrier.
//   ph2 stg buf A-kh0 : afA(prev ph3)/afB(ph0) reads confirmed ph1 LGKM(12)
//       + ph1 barrier.
//   ph3 stg buf B-kh1 : bfB read ph1, confirmed ph2 LGKM(4) + ph2 barrier.
// Gate: ph3 vmcnt(12) retires everything older than t+2's 3 streams ->
// all four t+1 streams landed; then barrier; then nbuf kh0 reads. Prologue
// issues 28 loads, vmcnt(12) = t0's 16 landed. Tail: t==NT-2 vmcnt(0).
// MFMA cluster ks-outer: 8 independent acc chains between dependent pairs
// (single wave/SIMD must self-feed the pipe).
// ---------------------------------------------------------------------------
__global__ __launch_bounds__(256, 1) void syrk8(const __bf16* __restrict__ Lb,
                                                float* __restrict__ C) {
  __shared__ __bf16 lds[2][2][2][256][32];  // [buf][ab][kh][row][k] 128 KiB

  const int bid0 = blockIdx.x;
  const int bid = (bid0 & 7) * 32 + (bid0 >> 3);  // bijective XCD chunking
  const int bi = bid >> 4, bj = bid & 15;

  const int tid = threadIdx.x;
  const int lane = tid & 63;
  const int wid = tid >> 6;   // 0..3
  const int wm = wid >> 1;    // 0..1 : rows wm*128..+127
  const int wn = wid & 1;     // 0..1 : cols wn*128..+127
  const int r32 = lane & 31;
  const int khi = lane >> 5;
  const int swzf = ((r32 >> 1) & 3) ^ ((lane >> 4) & 1);
  const int ck0 = ((0 | khi) ^ swzf) * 8;
  const int ck1 = ((2 | khi) ^ swzf) * 8;

  const size_t rowA0 = (size_t)bi * 256;
  const size_t rowB0 = (size_t)bj * 256;

  // staging: wave stages 64 rows (4 gloads x 16 rows); source chunk parity
  // follows (row>>4)&1 == q&1 (wid*64 keeps bit4 = q&1).
  const int srow = wid * 64 + (lane >> 2);
  const int sch = (lane & 3) ^ ((lane >> 3) & 3);
  const int soff0 = sch * 8;        // q even
  const int soff1 = (sch ^ 1) * 8;  // q odd

  const __bf16* g0 = Lb + (rowA0 + srow) * SIZE;       // A kh0 stream
  const __bf16* g1 = Lb + (rowB0 + srow) * SIZE;       // B kh0
  const __bf16* g2 = Lb + (rowA0 + srow) * SIZE + 32;  // A kh1
  const __bf16* g3 = Lb + (rowB0 + srow) * SIZE + 32;  // B kh1

  auto stg = [&](const __bf16*& gp, int ab, int kh, int dstbuf) {
    __bf16* base = &lds[dstbuf][ab][kh][0][0];
    gload_lds16(gp, base + (wid * 64) * 32);
    gload_lds16(gp + (size_t)16 * SIZE + (soff1 - soff0),
                base + (wid * 64 + 16) * 32);
    gload_lds16(gp + (size_t)32 * SIZE, base + (wid * 64 + 32) * 32);
    gload_lds16(gp + (size_t)48 * SIZE + (soff1 - soff0),
                base + (wid * 64 + 48) * 32);
    gp += BK;
  };
  // fold soff0 into the stream pointers once
  g0 += soff0; g1 += soff0; g2 += soff0; g3 += soff0;

  f32x16 acc[4][4] = {};                       // [row_blk 0..3][nb 0..3]
  bf16x8 afA[2][2], afB[2][2], bfA[4][2], bfB[4][2];  // [block][ks]

// 4 ds_read_b128: A fragments, m-half MH of this wave's 128 rows
#define LDA(AF, BSEL, KH, MH)                                              \
  {                                                                        \
    _Pragma("unroll") for (int mb = 0; mb < 2; ++mb) {                     \
      const __bf16* ap =                                                   \
          &lds[BSEL][0][KH][wm * 128 + ((MH)*2 + mb) * 32 + r32][0];       \
      AF[mb][0] = *(const bf16x8*)(ap + ck0);                              \
      AF[mb][1] = *(const bf16x8*)(ap + ck1);                              \
    }                                                                      \
  }
// 8 ds_read_b128: full B set (4 nb) for half-K KH, reused across mh phases
#define LDB(BF, BSEL, KH)                                                  \
  {                                                                        \
    _Pragma("unroll") for (int nb = 0; nb < 4; ++nb) {                     \
      const __bf16* bp = &lds[BSEL][1][KH][wn * 128 + nb * 32 + r32][0];   \
      BF[nb][0] = *(const bf16x8*)(bp + ck0);                              \
      BF[nb][1] = *(const bf16x8*)(bp + ck1);                              \
    }                                                                      \
  }

// 16 MFMA, ks-outer (max dep distance: 8 independent chains per ks wave)
#define MMA(AF, BF, MH)                                                    \
  {                                                                        \
    __builtin_amdgcn_s_setprio(1);                                         \
    _Pragma("unroll") for (int ks = 0; ks < 2; ++ks)                       \
        _Pragma("unroll") for (int mb = 0; mb < 2; ++mb)                   \
            _Pragma("unroll") for (int nb = 0; nb < 4; ++nb)               \
                acc[(MH)*2 + mb][nb] =                                     \
        __builtin_amdgcn_mfma_f32_32x32x16_bf16(AF[mb][ks], BF[nb][ks],    \
                                                acc[(MH)*2 + mb][nb], 0,   \
                                                0, 0);                     \
    __builtin_amdgcn_s_setprio(0);                                         \
  }

#define LGKM(N)                                                            \
  asm volatile("s_waitcnt lgkmcnt(" #N ")" ::: "memory");                  \
  __builtin_amdgcn_sched_barrier(0)

  // prologue: t0 all 4 streams (buf0) + t1 {B-kh0, A-kh0, B-kh1} (buf1)
  stg(g0, 0, 0, 0); stg(g1, 1, 0, 0); stg(g2, 0, 1, 0); stg(g3, 1, 1, 0);
  stg(g1, 1, 0, 1); stg(g0, 0, 0, 1); stg(g3, 1, 1, 1);
  asm volatile("s_waitcnt vmcnt(12)" ::: "memory");  // t0's 16 landed
  __builtin_amdgcn_s_barrier();
  LDA(afA, 0, 0, 0);  // ph(kh0,mh0) operands; confirmed by first LGKM(4)
  LDB(bfA, 0, 0);

  for (int t = 0; t < NT; ++t) {
    const int buf = t & 1, nbuf = buf ^ 1;
    // ---- ph0: MFMA(afA,bfA -> kh0,mh0); read afB <- (buf,kh0,mh1) ----
    if (t < NT - 1) stg(g2, 0, 1, nbuf);  // A-kh1 for t+1
    LDA(afB, buf, 0, 1);
    LGKM(4);
    MMA(afA, bfA, 0);
    __builtin_amdgcn_s_barrier();
    // ---- ph1: MFMA(afB,bfA -> kh0,mh1); read afA (buf,kh1,mh0) + bfB ----
    if (t < NT - 2) stg(g1, 1, 0, buf);   // B-kh0 for t+2
    LDA(afA, buf, 1, 0);
    LDB(bfB, buf, 1);
    LGKM(12);
    MMA(afB, bfA, 1);
    __builtin_amdgcn_s_barrier();
    // ---- ph2: MFMA(afA,bfB -> kh1,mh0); read afB <- (buf,kh1,mh1) ----
    if (t < NT - 2) stg(g0, 0, 0, buf);   // A-kh0 for t+2
    LDA(afB, buf, 1, 1);
    LGKM(4);
    MMA(afA, bfB, 0);
    __builtin_amdgcn_s_barrier();
    // ---- ph3: gate; MFMA(afB,bfB -> kh1,mh1); read next tile kh0 sets ----
    if (t < NT - 2) {
      stg(g3, 1, 1, buf);                 // B-kh1 for t+2
      asm volatile("s_waitcnt vmcnt(12)" ::: "memory");
    } else if (t == NT - 2) {
      asm volatile("s_waitcnt vmcnt(0)" ::: "memory");
    }
    __builtin_amdgcn_s_barrier();         // all waves' t+1 loads landed
    if (t < NT - 1) {
      LDA(afA, nbuf, 0, 0);
      LDB(bfA, nbuf, 0);
      LGKM(12);
    } else {
      LGKM(0);
    }
    MMA(afB, bfB, 1);
    __builtin_amdgcn_s_barrier();
  }

  // C/D layout (m74/m101): col = lane&31, row = (j&3) + 8*(j>>2) + 4*(lane>>5)
  float* Cp = C + (rowA0 + wm * 128) * (size_t)SIZE + rowB0 + wn * 128;
#pragma unroll
  for (int a = 0; a < 4; ++a)
#pragma unroll
    for (int nb = 0; nb < 4; ++nb)
#pragma unroll
      for (int j = 0; j < 16; ++j)
        Cp[(size_t)(a * 32 + (j & 3) + 8 * (j >> 2) + 4 * khi) * SIZE +
           nb * 32 + r32] = acc[a][nb][j];
#undef LDA
#undef LDB
#undef MMA
#undef LGKM
}

// ---------------------------------------------------------------------------
extern "C" void kernel_launch(void* const* d_in, const int* in_sizes, int n_in,
                              void* d_out, int out_size, void* d_ws, size_t ws_size,
                              hipStream_t stream) {
  const float* p = (const float*)d_in[0];
  float* C = (float*)d_out;
  __bf16* Lb = (__bf16*)d_ws;  // 32 MB scratch

  build_L<<<SIZE, 256, 0, stream>>>(p, Lb);
  syrk8<<<NBG * NBG, 256, 0, stream>>>(Lb, C);
}

// Round 11
// 130.535 us; speedup vs baseline: 1.0171x; 1.0171x over previous
//
#include <hip/hip_runtime.h>
#include <hip/hip_bf16.h>

#define SIZE 4096
#define BM 256
#define BK 64
#define NT (SIZE / BK)     // 64 K-tiles
#define NBG (SIZE / BM)    // 16x16 grid of 256^2 tiles

typedef __bf16 bf16x8 __attribute__((ext_vector_type(8)));
typedef __bf16 bf16x4 __attribute__((ext_vector_type(4)));
typedef float f32x4 __attribute__((ext_vector_type(4)));

__device__ __forceinline__ void gload_lds16(const void* gsrc, void* ldst) {
  __builtin_amdgcn_global_load_lds(
      (const __attribute__((address_space(1))) unsigned int*)gsrc,
      (__attribute__((address_space(3))) unsigned int*)ldst, 16, 0, 0);
}

// ---------------------------------------------------------------------------
// Kernel 1: build L (bf16), single pass. One 256-thread block per row,
// 16 consecutive cols per thread. Per-thread serial prefix product +
// one wave shfl-scan + one LDS cross-wave combine: 2 barriers total.
// fp32 throughout (matches reference underflow-to-0 behavior).
// ---------------------------------------------------------------------------
__global__ __launch_bounds__(256) void build_L(const float* __restrict__ p,
                                               __bf16* __restrict__ Lb) {
  const int row = blockIdx.x;
  const int tid = threadIdx.x;
  const int lane = tid & 63;
  const int wid = tid >> 6;
  const long base = (long)row * (row - 1) / 2;
  const int jb = tid * 16;

  float t[16], v[16];
  if (jb + 15 < row) {
    // fully strict-lower: vector loads + 16 tanh
#pragma unroll
    for (int q = 0; q < 4; ++q) {
      const f32x4 pv = *reinterpret_cast<const f32x4*>(&p[base + jb + q * 4]);
#pragma unroll
      for (int e = 0; e < 4; ++e) {
        const float th = tanhf(pv[e]);
        t[q * 4 + e] = th;
        v[q * 4 + e] = 1.0f - th * th;
      }
    }
  } else {
    // boundary / upper threads: per-element predicates
#pragma unroll
    for (int e = 0; e < 16; ++e) {
      const int j = jb + e;
      if (j < row) {
        const float th = tanhf(p[base + j]);
        t[e] = th;
        v[e] = 1.0f - th * th;
      } else {
        t[e] = (j == row) ? 1.0f : 0.0f;  // diag z=1, upper 0
        v[e] = 1.0f;
      }
    }
  }
  // per-thread total product
  float prod = 1.0f;
#pragma unroll
  for (int e = 0; e < 16; ++e) prod *= v[e];
  // wave inclusive scan (product) of thread totals
  float incl = prod;
#pragma unroll
  for (int off = 1; off < 64; off <<= 1) {
    float o = __shfl_up(incl, off, 64);
    if (lane >= off) incl *= o;
  }
  __shared__ float wtot[4];
  if (lane == 63) wtot[wid] = incl;
  __syncthreads();
  float pre = 1.0f;
  for (int w = 0; w < wid; ++w) pre *= wtot[w];
  float excl = __shfl_up(incl, 1, 64);
  if (lane == 0) excl = 1.0f;
  float s = pre * excl;  // exclusive prefix product up to jb

  bf16x8 out0, out1;
#pragma unroll
  for (int e = 0; e < 8; ++e) {
    out0[e] = (__bf16)(t[e] * sqrtf(s));
    s *= v[e];
  }
#pragma unroll
  for (int e = 0; e < 8; ++e) {
    out1[e] = (__bf16)(t[8 + e] * sqrtf(s));
    s *= v[8 + e];
  }
  __bf16* dst = Lb + (size_t)row * SIZE + jb;  // 32B-aligned
  *reinterpret_cast<bf16x8*>(dst) = out0;
  *reinterpret_cast<bf16x8*>(dst + 8) = out1;
}

// ---------------------------------------------------------------------------
// Kernel 2: C = L*L^T — REVERT to the best-measured variant (R5: 114.4 us,
// MfmaUtil 49.5, 0 bank conflicts). 256x256 tile, BK=64, 8 waves (2Mx4N),
// 4-phase/K-tile m201-style skeleton, 16x16x32 MFMA, K-split LDS halves
// [kh][256][32], chunk-XOR swizzle (storage chunk c holds logical chunk
// c^((row>>1)&3); both-sides rule: inverse-permuted global source).
// Phases split by (kh, m-half): ds_reads 8/4/8/4.
// ---------------------------------------------------------------------------
__global__ __launch_bounds__(512, 1) void syrk8(const __bf16* __restrict__ Lb,
                                                float* __restrict__ C) {
  // [buf][ab][kh][row][k] : 2*2*2*256*32*2B = 128 KiB
  __shared__ __bf16 lds[2][2][2][256][32];

  // XCD-chunk swizzle (bijective: 256 % 8 == 0)
  const int bid0 = blockIdx.x;
  const int bid = (bid0 & 7) * 32 + (bid0 >> 3);
  const int bi = bid >> 4, bj = bid & 15;

  const int tid = threadIdx.x;
  const int lane = tid & 63;
  const int wid = tid >> 6;  // 0..7
  const int wm = wid >> 2;   // 0..1 : rows wm*128..+127
  const int wn = wid & 3;    // 0..3 : cols wn*64..+63
  const int r16 = lane & 15;
  const int kg = lane >> 4;
  // swizzled chunk for LDS reads (row bits 1-2 == r16 bits 1-2 always)
  const int rdk = (kg ^ ((r16 >> 1) & 3)) * 8;

  const size_t rowA0 = (size_t)bi * 256;
  const size_t rowB0 = (size_t)bj * 256;

  // staging: wave stages 16 rows (64B each) per issue, 2 issues per half-tile
  const int srow = wid * 32 + (lane >> 2);
  const int schunk = (lane & 3) ^ ((lane >> 3) & 3);  // inverse-swz source

  // half h (global): tile = h>>2; sub = h&3 -> [A-kh0, B-kh0, A-kh1, B-kh1]
  auto stage = [&](int h) {
    if (h >= 4 * NT) return;
    const int tile = h >> 2, sub = h & 3;
    const int ab = sub & 1, kh = sub >> 1, buf = tile & 1;
    const size_t grow0 = ab ? rowB0 : rowA0;
    const int gk = tile * BK + kh * 32;
    const __bf16* gsrc = Lb + (grow0 + srow) * SIZE + gk + schunk * 8;
    __bf16* base = &lds[buf][ab][kh][0][0];
#pragma unroll
    for (int q = 0; q < 2; ++q)
      gload_lds16(gsrc + (size_t)q * 16 * SIZE, base + (wid * 32 + q * 16) * 32);
  };

  f32x4 acc[8][4] = {};

  // prologue: tile0 (4 halves) + tile1's first 3 halves
  for (int h = 0; h < 7; ++h) stage(h);
  asm volatile("s_waitcnt vmcnt(6)" ::: "memory");  // tile0 landed
  __builtin_amdgcn_s_barrier();

  for (int t = 0; t < NT; ++t) {
    const int buf = t & 1;
    bf16x8 af[4], bf[4];
#pragma unroll
    for (int i = 0; i < 4; ++i) {  // phase: (kh, mh) = (i>>1, i&1)
      const int kh = i >> 1, mh = i & 1;
      if (mh == 0) {  // B-frags for this kh: live across both m-half phases
#pragma unroll
        for (int n = 0; n < 4; ++n)
          bf[n] = *(const bf16x8*)&lds[buf][1][kh][wn * 64 + n * 16 + r16][rdk];
      }
#pragma unroll
      for (int m = 0; m < 4; ++m)
        af[m] = *(const bf16x8*)&lds[buf][0][kh]
                                    [wm * 128 + (mh * 4 + m) * 16 + r16][rdk];

      stage(4 * t + 7 + i);  // 1 half-tile prefetch per phase

      if (i == 3) {  // once per K-tile: gate next tile's data
        if (t == NT - 2)
          asm volatile("s_waitcnt vmcnt(0)" ::: "memory");
        else if (t < NT - 2)
          asm volatile("s_waitcnt vmcnt(6)" ::: "memory");
      }
      __builtin_amdgcn_s_barrier();
      asm volatile("s_waitcnt lgkmcnt(0)" ::: "memory");
      __builtin_amdgcn_sched_barrier(0);
      __builtin_amdgcn_s_setprio(1);
#pragma unroll
      for (int m = 0; m < 4; ++m)
#pragma unroll
        for (int n = 0; n < 4; ++n)
          acc[mh * 4 + m][n] = __builtin_amdgcn_mfma_f32_16x16x32_bf16(
              af[m], bf[n], acc[mh * 4 + m][n], 0, 0, 0);
      __builtin_amdgcn_s_setprio(0);
      __builtin_amdgcn_s_barrier();
    }
  }

  // C/D layout (m89): col = lane&15, row = kg*4 + reg
  float* Cp = C + (rowA0 + wm * 128) * (size_t)SIZE + rowB0 + wn * 64;
#pragma unroll
  for (int m = 0; m < 8; ++m)
#pragma unroll
    for (int n = 0; n < 4; ++n)
#pragma unroll
      for (int j = 0; j < 4; ++j)
        Cp[(size_t)(m * 16 + kg * 4 + j) * SIZE + n * 16 + r16] = acc[m][n][j];
}

// ---------------------------------------------------------------------------
extern "C" void kernel_launch(void* const* d_in, const int* in_sizes, int n_in,
                              void* d_out, int out_size, void* d_ws, size_t ws_size,
                              hipStream_t stream) {
  const float* p = (const float*)d_in[0];
  float* C = (float*)d_out;
  __bf16* Lb = (__bf16*)d_ws;  // 32 MB scratch

  build_L<<<SIZE, 256, 0, stream>>>(p, Lb);
  syrk8<<<NBG * NBG, 512, 0, stream>>>(Lb, C);
}